// Round 10
// baseline (858.223 us; speedup 1.0000x reference)
//
#include <hip/hip_runtime.h>

#define HID 128

typedef __attribute__((ext_vector_type(8))) short short8;
typedef __attribute__((ext_vector_type(8))) unsigned short ushort8v;
typedef __attribute__((ext_vector_type(4))) float floatx4;
typedef __attribute__((ext_vector_type(4))) unsigned short ushort4v;

__device__ __forceinline__ unsigned short f2bf(float f) {
    unsigned u = __builtin_bit_cast(unsigned, f);
    u += 0x7FFF + ((u >> 16) & 1);           // RNE
    return (unsigned short)(u >> 16);
}
__device__ __forceinline__ float bf2f(unsigned short s) {
    unsigned u = ((unsigned)s) << 16;
    return __builtin_bit_cast(float, u);
}

// ---------------- merged fill: rdeg (f32 0) + indeg (i32 0) ----------------
__global__ void fillrd_kernel(float* __restrict__ rdeg, int* __restrict__ indeg, int N)
{
    int i = blockIdx.x * 256 + threadIdx.x;
    if (i < N) { rdeg[i] = 0.f; indeg[i] = 0; }
}

// ---------------- diagnostic ----------------
__global__ void diag_kernel(float* __restrict__ out, long n, float val)
{
    long i = (long)blockIdx.x * blockDim.x + threadIdx.x;
    if (i < n) out[i] = val;
}

// ---------------- atom encoder: 8 nodes/block, 32 lanes x 4 cols -------------
__global__ __launch_bounds__(256) void encode_kernel(
    const int* __restrict__ x, const float* __restrict__ atom_emb,
    unsigned short* __restrict__ hb, int N)
{
    int n = blockIdx.x * 8 + (threadIdx.x >> 5);
    if (n >= N) return;
    int c = (threadIdx.x & 31) * 4;
    const int OFF[9] = {0, 119, 123, 135, 147, 157, 163, 169, 171};
    floatx4 s = {0.f, 0.f, 0.f, 0.f};
#pragma unroll
    for (int f = 0; f < 9; ++f) {
        int idx = x[n * 9 + f] + OFF[f];
        floatx4 v = *reinterpret_cast<const floatx4*>(atom_emb + (long)idx * HID + c);
#pragma unroll
        for (int j = 0; j < 4; ++j) s[j] += v[j];
    }
    ushort4v o;
#pragma unroll
    for (int j = 0; j < 4; ++j) o[j] = f2bf(s[j]);
    *reinterpret_cast<ushort4v*>(hb + (long)n * HID + c) = o;
}

// ---------------- fp32 -> bf16 table convert ----------------
__global__ void cvtW_kernel(const float* __restrict__ W, unsigned short* __restrict__ Wb)
{
    int i = blockIdx.x * 256 + threadIdx.x;
    if (i < HID * HID) Wb[i] = f2bf(W[i]);
}

// ---------------- bond combo table (60x128) + folded BN params ---------------
__global__ __launch_bounds__(128) void combemb_kernel(
    const float* __restrict__ bond_emb, float* __restrict__ comb,
    const float* __restrict__ gamma, const float* __restrict__ beta,
    const float* __restrict__ mean, const float* __restrict__ var,
    float* __restrict__ bnsc, float* __restrict__ bnsh)
{
    int i = blockIdx.x;
    int c = threadIdx.x;
    if (i < 60) {
        int a0 = i / 12, a1 = (i % 12) / 2, a2 = i % 2;
        comb[i * HID + c] = bond_emb[a0 * HID + c] + bond_emb[(5 + a1) * HID + c]
                          + bond_emb[(11 + a2) * HID + c];
    } else {
        float sc = gamma[c] * rsqrtf(var[c] + 1e-5f);
        bnsc[c] = sc;
        bnsh[c] = beta[c] - mean[c] * sc;
    }
}

// ---------------- merged: out-degree (row) + in-degree histogram (col) -------
__global__ void hist_kernel(const int* __restrict__ ei, float* __restrict__ deg,
                            int* __restrict__ indeg, int E)
{
    for (int e = blockIdx.x * blockDim.x + threadIdx.x; e < E; e += gridDim.x * blockDim.x) {
        atomicAdd(&deg[ei[e]], 1.f);
        atomicAdd(&indeg[ei[E + e]], 1);
    }
}

// deg -> rdeg (1/deg) in place, dis = deg^-0.5
__global__ void fdeg_kernel(float* __restrict__ deg, float* __restrict__ dis, int N)
{
    int n = blockIdx.x * blockDim.x + threadIdx.x;
    if (n < N) {
        float d = deg[n] + 1.f;
        deg[n] = 1.f / d;
        dis[n] = rsqrtf(d);
    }
}

// ---------------- CSR scan chain ----------------
__global__ __launch_bounds__(256) void bsum_kernel(
    const int* __restrict__ indeg, int* __restrict__ partial, int N)
{
    __shared__ int s[256];
    int i = blockIdx.x * 256 + threadIdx.x;
    s[threadIdx.x] = (i < N) ? indeg[i] : 0;
    __syncthreads();
    for (int d = 128; d > 0; d >>= 1) {
        if (threadIdx.x < d) s[threadIdx.x] += s[threadIdx.x + d];
        __syncthreads();
    }
    if (threadIdx.x == 0) partial[blockIdx.x] = s[0];
}

__global__ __launch_bounds__(256) void scan1_kernel(
    const int* __restrict__ partial, int* __restrict__ offs,
    int* __restrict__ ptr, int B, int N)
{
    __shared__ int s[256];
    __shared__ int carry_s;
    int tid = threadIdx.x;
    if (tid == 0) carry_s = 0;
    __syncthreads();
    for (int base = 0; base < B; base += 256) {
        int i = base + tid;
        int v = (i < B) ? partial[i] : 0;
        s[tid] = v;
        __syncthreads();
        for (int d = 1; d < 256; d <<= 1) {
            int t = (tid >= d) ? s[tid - d] : 0;
            __syncthreads();
            s[tid] += t;
            __syncthreads();
        }
        int carry = carry_s;
        if (i < B) offs[i] = carry + s[tid] - v;
        __syncthreads();
        if (tid == 0) carry_s = carry + s[255];
        __syncthreads();
    }
    if (tid == 0) ptr[N] = carry_s;
}

__global__ __launch_bounds__(256) void scan2_kernel(
    const int* __restrict__ indeg, const int* __restrict__ offs,
    int* __restrict__ ptr, int* __restrict__ cursor, int N)
{
    __shared__ int s[256];
    int tid = threadIdx.x;
    int i = blockIdx.x * 256 + tid;
    int v = (i < N) ? indeg[i] : 0;
    s[tid] = v;
    __syncthreads();
    for (int d = 1; d < 256; d <<= 1) {
        int t = (tid >= d) ? s[tid - d] : 0;
        __syncthreads();
        s[tid] += t;
        __syncthreads();
    }
    if (i < N) {
        int ex = offs[blockIdx.x] + s[tid] - v;
        ptr[i] = ex;
        cursor[i] = ex;
    }
}

// ---------------- CSR fill + per-edge record {row, ci, norm} ----------------
__global__ void fillcsr_kernel(const int* __restrict__ ei, const int* __restrict__ attr,
                               const float* __restrict__ dis, int* __restrict__ cursor,
                               int4* __restrict__ edata, int E)
{
    for (int e = blockIdx.x * blockDim.x + threadIdx.x; e < E; e += gridDim.x * blockDim.x) {
        int r   = ei[e];
        int col = ei[E + e];
        int pos = atomicAdd(&cursor[col], 1);
        int ci  = attr[e * 3] * 12 + attr[e * 3 + 1] * 2 + attr[e * 3 + 2];
        float nrm = dis[r] * dis[col];
        int4 ed;
        ed.x = r; ed.y = ci; ed.z = __builtin_bit_cast(int, nrm); ed.w = 0;
        edata[pos] = ed;
    }
}

// ---------------- graph boundaries ----------------
__global__ void gptr_kernel(const int* __restrict__ batch, int* __restrict__ gptr,
                            int N, int G)
{
    int n = blockIdx.x * blockDim.x + threadIdx.x;
    if (n >= N) return;
    int b = batch[n];
    int bp = (n == 0) ? -1 : batch[n - 1];
    for (int g = bp + 1; g <= b; ++g) gptr[g] = n;
    if (n == N - 1)
        for (int g = b + 1; g <= G; ++g) gptr[g] = N;
}

// ---------------- z = h @ W^T + b  (bf16 MFMA; LDS-repacked coalesced stores) --
__global__ __launch_bounds__(256) void gemm_kernel(
    const unsigned short* __restrict__ hb, const unsigned short* __restrict__ Wb,
    const float* __restrict__ bias, unsigned short* __restrict__ zb, int N)
{
    __shared__ unsigned short st[128][132];
    int wave = threadIdx.x >> 6;
    int lane = threadIdx.x & 63;
    int l15 = lane & 15;
    int q = lane >> 4;
    long row0 = (long)blockIdx.x * 128 + wave * 32;

    short8 a[2][4];
#pragma unroll
    for (int mt = 0; mt < 2; ++mt) {
        long rl = row0 + mt * 16 + l15;
        if (rl > (long)N - 1) rl = (long)N - 1;
        const unsigned short* ap = hb + rl * HID + q * 8;
#pragma unroll
        for (int kb = 0; kb < 4; ++kb)
            a[mt][kb] = *reinterpret_cast<const short8*>(ap + kb * 32);
    }

    floatx4 acc[2][8];
#pragma unroll
    for (int mt = 0; mt < 2; ++mt)
#pragma unroll
        for (int nt = 0; nt < 8; ++nt) {
            floatx4 zz = {0.f, 0.f, 0.f, 0.f};
            acc[mt][nt] = zz;
        }

#pragma unroll
    for (int nt = 0; nt < 8; ++nt) {
        const unsigned short* bp = Wb + (nt * 16 + l15) * HID + q * 8;
#pragma unroll
        for (int kb = 0; kb < 4; ++kb) {
            short8 b = *reinterpret_cast<const short8*>(bp + kb * 32);
            acc[0][nt] = __builtin_amdgcn_mfma_f32_16x16x32_bf16(a[0][kb], b, acc[0][nt], 0, 0, 0);
            acc[1][nt] = __builtin_amdgcn_mfma_f32_16x16x32_bf16(a[1][kb], b, acc[1][nt], 0, 0, 0);
        }
    }

    float bi[8];
#pragma unroll
    for (int nt = 0; nt < 8; ++nt) bi[nt] = bias[nt * 16 + l15];

#pragma unroll
    for (int mt = 0; mt < 2; ++mt)
#pragma unroll
        for (int r = 0; r < 4; ++r) {
            int lr = wave * 32 + mt * 16 + q * 4 + r;
#pragma unroll
            for (int nt = 0; nt < 8; ++nt)
                st[lr][l15 + 16 * nt] = f2bf(acc[mt][nt][r] + bi[nt]);
        }
    __syncthreads();

    int tr = threadIdx.x >> 4;
    int tc = (threadIdx.x & 15) * 8;
#pragma unroll
    for (int i = 0; i < 8; ++i) {
        int row = i * 16 + tr;
        long gr = (long)blockIdx.x * 128 + row;
        if (gr < N) {
            ushort8v v = *reinterpret_cast<const ushort8v*>(&st[row][tc]);
            *reinterpret_cast<ushort8v*>(zb + gr * HID + tc) = v;
        }
    }
}

// ---------------- final linear via MFMA ----------------
__global__ __launch_bounds__(256) void linmm_kernel(
    const unsigned short* __restrict__ pb, const unsigned short* __restrict__ Wb,
    const float* __restrict__ bias, float* __restrict__ out, int G)
{
    int wave = threadIdx.x >> 6;
    int lane = threadIdx.x & 63;
    int l15 = lane & 15;
    int q = lane >> 4;
    long row0 = (long)blockIdx.x * 128 + wave * 32;

    short8 a[2][4];
#pragma unroll
    for (int mt = 0; mt < 2; ++mt) {
        long rl = row0 + mt * 16 + l15;
        if (rl > (long)G - 1) rl = (long)G - 1;
        const unsigned short* ap = pb + rl * HID + q * 8;
#pragma unroll
        for (int kb = 0; kb < 4; ++kb)
            a[mt][kb] = *reinterpret_cast<const short8*>(ap + kb * 32);
    }

    floatx4 acc[2][8];
#pragma unroll
    for (int mt = 0; mt < 2; ++mt)
#pragma unroll
        for (int nt = 0; nt < 8; ++nt) {
            floatx4 zz = {0.f, 0.f, 0.f, 0.f};
            acc[mt][nt] = zz;
        }

#pragma unroll
    for (int nt = 0; nt < 8; ++nt) {
        const unsigned short* bp = Wb + (nt * 16 + l15) * HID + q * 8;
#pragma unroll
        for (int kb = 0; kb < 4; ++kb) {
            short8 b = *reinterpret_cast<const short8*>(bp + kb * 32);
            acc[0][nt] = __builtin_amdgcn_mfma_f32_16x16x32_bf16(a[0][kb], b, acc[0][nt], 0, 0, 0);
            acc[1][nt] = __builtin_amdgcn_mfma_f32_16x16x32_bf16(a[1][kb], b, acc[1][nt], 0, 0, 0);
        }
    }

    float bi[8];
#pragma unroll
    for (int nt = 0; nt < 8; ++nt) bi[nt] = bias[nt * 16 + l15];

#pragma unroll
    for (int mt = 0; mt < 2; ++mt)
#pragma unroll
        for (int r = 0; r < 4; ++r) {
            long rr = row0 + mt * 16 + q * 4 + r;
            if (rr < G) {
                float* op = out + rr * HID + l15;
#pragma unroll
                for (int nt = 0; nt < 8; ++nt)
                    op[nt * 16] = acc[mt][nt][r] + bi[nt];
            }
        }
}

// ---------------- fused: self-term + CSR gather + relu + BN + combine -------
// 8 lanes/node x 16 cols: 8 independent node-chains per wave, 32 nodes/block.
// 2-way edge unroll; folded BN (sc, sh); old-h load hoisted above edge loop.
template<bool FIRST>
__global__ __launch_bounds__(256) void agg_kernel(
    const int* __restrict__ ptr, const int4* __restrict__ edata,
    const float* __restrict__ comb,
    const float* __restrict__ rdeg, const float* __restrict__ root,
    const float* __restrict__ bnsc, const float* __restrict__ bnsh,
    const unsigned short* __restrict__ zb, unsigned short* __restrict__ hb,
    float fi, int N)
{
    int n = blockIdx.x * 32 + (threadIdx.x >> 3);
    if (n >= N) return;
    int c = (threadIdx.x & 7) * 16;

    const unsigned short* zp = zb + (long)n * HID + c;
    ushort8v zv0 = *reinterpret_cast<const ushort8v*>(zp);
    ushort8v zv1 = *reinterpret_cast<const ushort8v*>(zp + 8);

    unsigned short* hp = hb + (long)n * HID + c;
    ushort8v hv0, hv1;
    if constexpr (!FIRST) {                       // hoisted: overlaps gather latency
        hv0 = *reinterpret_cast<const ushort8v*>(hp);
        hv1 = *reinterpret_cast<const ushort8v*>(hp + 8);
    }

    float rd = rdeg[n];
    float acc[16];
#pragma unroll
    for (int j = 0; j < 8; ++j) {
        acc[j]     = fmaxf(bf2f(zv0[j]) + root[c + j],     0.f) * rd;
        acc[j + 8] = fmaxf(bf2f(zv1[j]) + root[c + 8 + j], 0.f) * rd;
    }

    int jb = ptr[n], je = ptr[n + 1];
    int j2 = jb;
    for (; j2 + 1 < je; j2 += 2) {
        int4 e0 = edata[j2];
        int4 e1 = edata[j2 + 1];
        const unsigned short* q0 = zb + (long)e0.x * HID + c;
        const unsigned short* q1 = zb + (long)e1.x * HID + c;
        ushort8v z00 = *reinterpret_cast<const ushort8v*>(q0);
        ushort8v z01 = *reinterpret_cast<const ushort8v*>(q0 + 8);
        ushort8v z10 = *reinterpret_cast<const ushort8v*>(q1);
        ushort8v z11 = *reinterpret_cast<const ushort8v*>(q1 + 8);
        const float* c0 = comb + e0.y * HID + c;
        const float* c1 = comb + e1.y * HID + c;
        float n0 = __builtin_bit_cast(float, e0.z);
        float n1 = __builtin_bit_cast(float, e1.z);
#pragma unroll
        for (int j = 0; j < 8; ++j) {
            acc[j]     += fmaxf(bf2f(z00[j]) + c0[j],     0.f) * n0;
            acc[j + 8] += fmaxf(bf2f(z01[j]) + c0[8 + j], 0.f) * n0;
            acc[j]     += fmaxf(bf2f(z10[j]) + c1[j],     0.f) * n1;
            acc[j + 8] += fmaxf(bf2f(z11[j]) + c1[8 + j], 0.f) * n1;
        }
    }
    if (j2 < je) {
        int4 e0 = edata[j2];
        const unsigned short* q0 = zb + (long)e0.x * HID + c;
        ushort8v z00 = *reinterpret_cast<const ushort8v*>(q0);
        ushort8v z01 = *reinterpret_cast<const ushort8v*>(q0 + 8);
        const float* c0 = comb + e0.y * HID + c;
        float n0 = __builtin_bit_cast(float, e0.z);
#pragma unroll
        for (int j = 0; j < 8; ++j) {
            acc[j]     += fmaxf(bf2f(z00[j]) + c0[j],     0.f) * n0;
            acc[j + 8] += fmaxf(bf2f(z01[j]) + c0[8 + j], 0.f) * n0;
        }
    }

    ushort8v o0, o1;
#pragma unroll
    for (int j = 0; j < 8; ++j) {
        float t0 = fmaxf(acc[j],     0.f) * bnsc[c + j]     + bnsh[c + j];
        float t1 = fmaxf(acc[j + 8], 0.f) * bnsc[c + 8 + j] + bnsh[c + 8 + j];
        float h0, h1;
        if constexpr (FIRST) { h0 = t0; h1 = t1; }
        else {
            h0 = fi * bf2f(hv0[j]) + (1.f - fi) * t0;
            h1 = fi * bf2f(hv1[j]) + (1.f - fi) * t1;
        }
        o0[j] = f2bf(h0);
        o1[j] = f2bf(h1);
    }
    *reinterpret_cast<ushort8v*>(hp)     = o0;
    *reinterpret_cast<ushort8v*>(hp + 8) = o1;
}

// ---------------- mean-pool per graph -> bf16 pooled[G][128] ----------------
__global__ __launch_bounds__(256) void pool_kernel(
    const unsigned short* __restrict__ hb, const int* __restrict__ gptr,
    unsigned short* __restrict__ pb, int G)
{
    int g = blockIdx.x;
    if (g >= G) return;
    int tid = threadIdx.x;
    int sub = tid >> 5;
    int c = (tid & 31) * 4;
    int lo = gptr[g], hi = gptr[g + 1];
    floatx4 s = {0.f, 0.f, 0.f, 0.f};
    for (int n = lo + sub; n < hi; n += 8) {
        ushort4v hv = *reinterpret_cast<const ushort4v*>(hb + (long)n * HID + c);
#pragma unroll
        for (int j = 0; j < 4; ++j) s[j] += bf2f(hv[j]);
    }
    __shared__ float ps[8][HID];
    *reinterpret_cast<floatx4*>(&ps[sub][c]) = s;
    __syncthreads();
    if (tid < HID) {
        float sum = 0.f;
#pragma unroll
        for (int k = 0; k < 8; ++k) sum += ps[k][tid];
        float cnt = (hi > lo) ? (float)(hi - lo) : 1.f;
        pb[(long)g * HID + tid] = f2bf(sum / cnt);
    }
}

extern "C" void kernel_launch(void* const* d_in, const int* in_sizes, int n_in,
                              void* d_out, int out_size, void* d_ws, size_t ws_size,
                              hipStream_t stream)
{
    const int* x          = (const int*)d_in[0];
    const int* ei         = (const int*)d_in[1];
    const int* attr       = (const int*)d_in[2];
    const int* batch      = (const int*)d_in[3];
    const float* atom_emb = (const float*)d_in[4];
    const float* bond_emb = (const float*)d_in[5];
    const float* conv_W   = (const float*)d_in[6];
    const float* conv_b   = (const float*)d_in[7];
    const float* root     = (const float*)d_in[8];
    const float* gamma    = (const float*)d_in[9];
    const float* beta     = (const float*)d_in[10];
    const float* mean     = (const float*)d_in[11];
    const float* var      = (const float*)d_in[12];
    const float* lin_W    = (const float*)d_in[13];
    const float* lin_b    = (const float*)d_in[14];
    float* out = (float*)d_out;

    const int N = in_sizes[0] / 9;
    const int E = in_sizes[1] / 2;
    const int G = out_size / HID;
    const int B = (N + 255) / 256;

    auto al = [](size_t b) { return (b + 255) & ~(size_t)255; };
    const size_t need =
        al((size_t)N * HID * 2) +         // hb
        al((size_t)N * HID * 2) +         // zb
        al((size_t)(N + 1) * 4) +         // ptr
        al((size_t)N * 4) +               // cursor
        al((size_t)E * 16) +              // edata
        al((size_t)N * 4) +               // indeg
        al((size_t)2048 * 4) * 2 +        // partial + offs
        al((size_t)N * 4) * 2 +           // rdeg + dis
        al((size_t)(G + 1) * 4) +         // gptr
        al((size_t)(G + 128) * HID * 2) + // pooled bf16 (+tail pad)
        al((size_t)60 * HID * 4) +        // comb
        al((size_t)HID * 4) * 2 +         // bnsc + bnsh
        al((size_t)HID * HID * 2) * 2;    // Wb + linWb

    if (ws_size < need || B > 2048) {
        float v = (B > 2048) ? 3000.f : (1000.f + (float)(ws_size >> 20));
        long n = (long)out_size;
        diag_kernel<<<(int)((n + 255) / 256), 256, 0, stream>>>(out, n, v);
        return;
    }

    char* wsp = (char*)d_ws;
    size_t used = 0;
    auto alloc = [&](size_t bytes) { char* p = wsp + used; used += al(bytes); return p; };
    unsigned short* hb = (unsigned short*)alloc((size_t)N * HID * 2);
    unsigned short* zb = (unsigned short*)alloc((size_t)N * HID * 2);
    int* ptr     = (int*)alloc((size_t)(N + 1) * 4);
    int* cursor  = (int*)alloc((size_t)N * 4);
    int4* edata  = (int4*)alloc((size_t)E * 16);
    int* indeg   = (int*)alloc((size_t)N * 4);
    int* partial = (int*)alloc((size_t)2048 * 4);
    int* offs    = (int*)alloc((size_t)2048 * 4);
    float* rdeg  = (float*)alloc((size_t)N * 4);
    float* dis   = (float*)alloc((size_t)N * 4);
    int* gptr    = (int*)alloc((size_t)(G + 1) * 4);
    unsigned short* pb = (unsigned short*)alloc((size_t)(G + 128) * HID * 2);
    float* comb  = (float*)alloc((size_t)60 * HID * 4);
    float* bnsc  = (float*)alloc((size_t)HID * 4);
    float* bnsh  = (float*)alloc((size_t)HID * 4);
    unsigned short* Wb    = (unsigned short*)alloc((size_t)HID * HID * 2);
    unsigned short* linWb = (unsigned short*)alloc((size_t)HID * HID * 2);

    // ---- prologue ----
    fillrd_kernel<<<B, 256, 0, stream>>>(rdeg, indeg, N);
    cvtW_kernel<<<(HID * HID + 255) / 256, 256, 0, stream>>>(conv_W, Wb);
    cvtW_kernel<<<(HID * HID + 255) / 256, 256, 0, stream>>>(lin_W, linWb);
    combemb_kernel<<<61, 128, 0, stream>>>(bond_emb, comb, gamma, beta, mean, var, bnsc, bnsh);
    encode_kernel<<<(N + 7) / 8, 256, 0, stream>>>(x, atom_emb, hb, N);
    hist_kernel<<<1024, 256, 0, stream>>>(ei, rdeg, indeg, E);
    fdeg_kernel<<<B, 256, 0, stream>>>(rdeg, dis, N);
    bsum_kernel<<<B, 256, 0, stream>>>(indeg, partial, N);
    scan1_kernel<<<1, 256, 0, stream>>>(partial, offs, ptr, B, N);
    scan2_kernel<<<B, 256, 0, stream>>>(indeg, offs, ptr, cursor, N);
    fillcsr_kernel<<<1024, 256, 0, stream>>>(ei, attr, dis, cursor, edata, E);
    gptr_kernel<<<B, 256, 0, stream>>>(batch, gptr, N, G);

    // ---- loop (i=1 is identity: h = 1*old + 0*z, skipped) ----
    const float fis[4] = {0.f, 2.f, 3.f, 4.f};
    const int gemm_blocks = (N + 127) / 128;
    const int agg_blocks = (N + 31) / 32;
    for (int t = 0; t < 4; ++t) {
        gemm_kernel<<<gemm_blocks, 256, 0, stream>>>(hb, Wb, conv_b, zb, N);
        if (t == 0)
            agg_kernel<true ><<<agg_blocks, 256, 0, stream>>>(ptr, edata, comb, rdeg, root,
                                                              bnsc, bnsh, zb, hb, fis[t], N);
        else
            agg_kernel<false><<<agg_blocks, 256, 0, stream>>>(ptr, edata, comb, rdeg, root,
                                                              bnsc, bnsh, zb, hb, fis[t], N);
    }

    // ---- mean-pool (bf16) + MFMA final linear (fp32 out) ----
    pool_kernel<<<G, 256, 0, stream>>>(hb, gptr, pb, G);
    linmm_kernel<<<(G + 127) / 128, 256, 0, stream>>>(pb, linWb, lin_b, out, G);
}

// Round 11
// 819.651 us; speedup vs baseline: 1.0471x; 1.0471x over previous
//
#include <hip/hip_runtime.h>

#define HID 128

typedef __attribute__((ext_vector_type(8))) short short8;
typedef __attribute__((ext_vector_type(8))) unsigned short ushort8v;
typedef __attribute__((ext_vector_type(4))) float floatx4;
typedef __attribute__((ext_vector_type(4))) unsigned short ushort4v;

__device__ __forceinline__ unsigned short f2bf(float f) {
    unsigned u = __builtin_bit_cast(unsigned, f);
    u += 0x7FFF + ((u >> 16) & 1);           // RNE
    return (unsigned short)(u >> 16);
}
__device__ __forceinline__ float bf2f(unsigned short s) {
    unsigned u = ((unsigned)s) << 16;
    return __builtin_bit_cast(float, u);
}

// ---------------- merged fill: dis (f32 0, deg accumulator) + indeg ----------
__global__ void fillrd_kernel(float* __restrict__ dis, int* __restrict__ indeg, int N)
{
    int i = blockIdx.x * 256 + threadIdx.x;
    if (i < N) { dis[i] = 0.f; indeg[i] = 0; }
}

// ---------------- diagnostic ----------------
__global__ void diag_kernel(float* __restrict__ out, long n, float val)
{
    long i = (long)blockIdx.x * blockDim.x + threadIdx.x;
    if (i < n) out[i] = val;
}

// ---------------- atom encoder ----------------
__global__ __launch_bounds__(256) void encode_kernel(
    const int* __restrict__ x, const float* __restrict__ atom_emb,
    unsigned short* __restrict__ hb, int N)
{
    int n = blockIdx.x * 8 + (threadIdx.x >> 5);
    if (n >= N) return;
    int c = (threadIdx.x & 31) * 4;
    const int OFF[9] = {0, 119, 123, 135, 147, 157, 163, 169, 171};
    floatx4 s = {0.f, 0.f, 0.f, 0.f};
#pragma unroll
    for (int f = 0; f < 9; ++f) {
        int idx = x[n * 9 + f] + OFF[f];
        floatx4 v = *reinterpret_cast<const floatx4*>(atom_emb + (long)idx * HID + c);
#pragma unroll
        for (int j = 0; j < 4; ++j) s[j] += v[j];
    }
    ushort4v o;
#pragma unroll
    for (int j = 0; j < 4; ++j) o[j] = f2bf(s[j]);
    *reinterpret_cast<ushort4v*>(hb + (long)n * HID + c) = o;
}

// ---------------- fp32 -> bf16 table convert ----------------
__global__ void cvtW_kernel(const float* __restrict__ W, unsigned short* __restrict__ Wb)
{
    int i = blockIdx.x * 256 + threadIdx.x;
    if (i < HID * HID) Wb[i] = f2bf(W[i]);
}

// ---------------- bond combo table (60x128) + folded BN params ---------------
__global__ __launch_bounds__(128) void combemb_kernel(
    const float* __restrict__ bond_emb, float* __restrict__ comb,
    const float* __restrict__ gamma, const float* __restrict__ beta,
    const float* __restrict__ mean, const float* __restrict__ var,
    float* __restrict__ bnsc, float* __restrict__ bnsh)
{
    int i = blockIdx.x;
    int c = threadIdx.x;
    if (i < 60) {
        int a0 = i / 12, a1 = (i % 12) / 2, a2 = i % 2;
        comb[i * HID + c] = bond_emb[a0 * HID + c] + bond_emb[(5 + a1) * HID + c]
                          + bond_emb[(11 + a2) * HID + c];
    } else {
        float sc = gamma[c] * rsqrtf(var[c] + 1e-5f);
        bnsc[c] = sc;
        bnsh[c] = beta[c] - mean[c] * sc;
    }
}

// ---------------- merged: out-degree (row, into dis) + in-degree (col) -------
__global__ void hist_kernel(const int* __restrict__ ei, float* __restrict__ dis,
                            int* __restrict__ indeg, int E)
{
    for (int e = blockIdx.x * blockDim.x + threadIdx.x; e < E; e += gridDim.x * blockDim.x) {
        atomicAdd(&dis[ei[e]], 1.f);
        atomicAdd(&indeg[ei[E + e]], 1);
    }
}

// dis (=outdeg count) -> deg^-0.5 in place. agg recovers 1/deg as dis^2.
__global__ void fdeg_kernel(float* __restrict__ dis, int N)
{
    int n = blockIdx.x * blockDim.x + threadIdx.x;
    if (n < N) dis[n] = rsqrtf(dis[n] + 1.f);
}

// ---------------- CSR scan chain ----------------
__global__ __launch_bounds__(256) void bsum_kernel(
    const int* __restrict__ indeg, int* __restrict__ partial, int N)
{
    __shared__ int s[256];
    int i = blockIdx.x * 256 + threadIdx.x;
    s[threadIdx.x] = (i < N) ? indeg[i] : 0;
    __syncthreads();
    for (int d = 128; d > 0; d >>= 1) {
        if (threadIdx.x < d) s[threadIdx.x] += s[threadIdx.x + d];
        __syncthreads();
    }
    if (threadIdx.x == 0) partial[blockIdx.x] = s[0];
}

__global__ __launch_bounds__(256) void scan1_kernel(
    const int* __restrict__ partial, int* __restrict__ offs,
    int* __restrict__ ptr, int B, int N)
{
    __shared__ int s[256];
    __shared__ int carry_s;
    int tid = threadIdx.x;
    if (tid == 0) carry_s = 0;
    __syncthreads();
    for (int base = 0; base < B; base += 256) {
        int i = base + tid;
        int v = (i < B) ? partial[i] : 0;
        s[tid] = v;
        __syncthreads();
        for (int d = 1; d < 256; d <<= 1) {
            int t = (tid >= d) ? s[tid - d] : 0;
            __syncthreads();
            s[tid] += t;
            __syncthreads();
        }
        int carry = carry_s;
        if (i < B) offs[i] = carry + s[tid] - v;
        __syncthreads();
        if (tid == 0) carry_s = carry + s[255];
        __syncthreads();
    }
    if (tid == 0) ptr[N] = carry_s;
}

// in-place safe: cursor may alias indeg (read-before-write per element)
__global__ __launch_bounds__(256) void scan2_kernel(
    const int* __restrict__ indeg, const int* __restrict__ offs,
    int* __restrict__ ptr, int* __restrict__ cursor, int N)
{
    __shared__ int s[256];
    int tid = threadIdx.x;
    int i = blockIdx.x * 256 + tid;
    int v = (i < N) ? indeg[i] : 0;
    s[tid] = v;
    __syncthreads();
    for (int d = 1; d < 256; d <<= 1) {
        int t = (tid >= d) ? s[tid - d] : 0;
        __syncthreads();
        s[tid] += t;
        __syncthreads();
    }
    if (i < N) {
        int ex = offs[blockIdx.x] + s[tid] - v;
        ptr[i] = ex;
        cursor[i] = ex;
    }
}

// ---------------- CSR fill: packed edge record {row, ci|bf16(norm)<<16} -------
__global__ void fillcsr_kernel(const int* __restrict__ ei, const int* __restrict__ attr,
                               const float* __restrict__ dis, int* __restrict__ cursor,
                               int2* __restrict__ edata, int E)
{
    for (int e = blockIdx.x * blockDim.x + threadIdx.x; e < E; e += gridDim.x * blockDim.x) {
        int r   = ei[e];
        int col = ei[E + e];
        int pos = atomicAdd(&cursor[col], 1);
        int ci  = attr[e * 3] * 12 + attr[e * 3 + 1] * 2 + attr[e * 3 + 2];
        float nrm = dis[r] * dis[col];
        int2 ed;
        ed.x = r;
        ed.y = ci | ((int)f2bf(nrm) << 16);
        edata[pos] = ed;
    }
}

// ---------------- graph boundaries ----------------
__global__ void gptr_kernel(const int* __restrict__ batch, int* __restrict__ gptr,
                            int N, int G)
{
    int n = blockIdx.x * blockDim.x + threadIdx.x;
    if (n >= N) return;
    int b = batch[n];
    int bp = (n == 0) ? -1 : batch[n - 1];
    for (int g = bp + 1; g <= b; ++g) gptr[g] = n;
    if (n == N - 1)
        for (int g = b + 1; g <= G; ++g) gptr[g] = N;
}

// ---------------- shared agg body: one node, 8 cols (16 lanes/node) ----------
template<bool FIRST>
__device__ __forceinline__ ushort8v agg_node(
    long n, int c, const int* __restrict__ ptr, const int2* __restrict__ edata,
    const float* __restrict__ comb, const float* __restrict__ dis,
    const float* __restrict__ root, const float* __restrict__ bnsc,
    const float* __restrict__ bnsh, const unsigned short* __restrict__ zb,
    const unsigned short* __restrict__ hb, float fi)
{
    ushort8v zv = *reinterpret_cast<const ushort8v*>(zb + n * HID + c);
    ushort8v hv;
    if constexpr (!FIRST) hv = *reinterpret_cast<const ushort8v*>(hb + n * HID + c);  // hoisted
    float di = dis[n];
    float rd = di * di;                       // 1/deg
    float acc[8];
#pragma unroll
    for (int j = 0; j < 8; ++j) acc[j] = fmaxf(bf2f(zv[j]) + root[c + j], 0.f) * rd;

    int jb = ptr[n], je = ptr[n + 1];
    int j2 = jb;
    for (; j2 + 1 < je; j2 += 2) {            // paired: 2 gathers in flight
        int2 e0 = edata[j2];
        int2 e1 = edata[j2 + 1];
        ushort8v z0 = *reinterpret_cast<const ushort8v*>(zb + (long)e0.x * HID + c);
        ushort8v z1 = *reinterpret_cast<const ushort8v*>(zb + (long)e1.x * HID + c);
        const float* c0 = comb + (e0.y & 0xFF) * HID + c;
        const float* c1 = comb + (e1.y & 0xFF) * HID + c;
        float n0 = bf2f((unsigned short)(((unsigned)e0.y) >> 16));
        float n1 = bf2f((unsigned short)(((unsigned)e1.y) >> 16));
#pragma unroll
        for (int j = 0; j < 8; ++j) {
            acc[j] += fmaxf(bf2f(z0[j]) + c0[j], 0.f) * n0;
            acc[j] += fmaxf(bf2f(z1[j]) + c1[j], 0.f) * n1;
        }
    }
    if (j2 < je) {
        int2 e0 = edata[j2];
        ushort8v z0 = *reinterpret_cast<const ushort8v*>(zb + (long)e0.x * HID + c);
        const float* c0 = comb + (e0.y & 0xFF) * HID + c;
        float n0 = bf2f((unsigned short)(((unsigned)e0.y) >> 16));
#pragma unroll
        for (int j = 0; j < 8; ++j) acc[j] += fmaxf(bf2f(z0[j]) + c0[j], 0.f) * n0;
    }

    ushort8v o;
#pragma unroll
    for (int j = 0; j < 8; ++j) {
        float t = fmaxf(acc[j], 0.f) * bnsc[c + j] + bnsh[c + j];
        float h;
        if constexpr (FIRST) h = t;
        else h = fi * bf2f(hv[j]) + (1.f - fi) * t;
        o[j] = f2bf(h);
    }
    return o;
}

// ---------------- standalone agg (final iteration: no z output) --------------
template<bool FIRST>
__global__ __launch_bounds__(256) void agg_kernel(
    const int* __restrict__ ptr, const int2* __restrict__ edata,
    const float* __restrict__ comb, const float* __restrict__ dis,
    const float* __restrict__ root, const float* __restrict__ bnsc,
    const float* __restrict__ bnsh, const unsigned short* __restrict__ zb,
    unsigned short* __restrict__ hb, float fi, int N)
{
    long n = (long)blockIdx.x * 16 + (threadIdx.x >> 4);
    if (n >= N) return;
    int c = (threadIdx.x & 15) * 8;
    ushort8v o = agg_node<FIRST>(n, c, ptr, edata, comb, dis, root, bnsc, bnsh, zb, hb, fi);
    *reinterpret_cast<ushort8v*>(hb + n * HID + c) = o;
}

// ---------------- fused agg + gemm: h_new (LDS) -> z_next = h W^T + b --------
// Phase A: 8 subtiles x 16 nodes (16 lanes/node, round-9 layout).
// Phase B: MFMA from LDS h-tile; C restaged through same LDS; coalesced store.
template<bool FIRST>
__global__ __launch_bounds__(256) void aggemm_kernel(
    const int* __restrict__ ptr, const int2* __restrict__ edata,
    const float* __restrict__ comb, const float* __restrict__ dis,
    const float* __restrict__ root, const float* __restrict__ bnsc,
    const float* __restrict__ bnsh,
    const unsigned short* __restrict__ zin, unsigned short* __restrict__ hb,
    const unsigned short* __restrict__ Wb, const float* __restrict__ bias,
    unsigned short* __restrict__ zout, float fi, int N)
{
    __shared__ unsigned short hs[128][132];   // +4 pad: rows land on shifted banks
    int tid = threadIdx.x;
    long base = (long)blockIdx.x * 128;

    // ---- Phase A ----
    int sn = tid >> 4;
    int cc = (tid & 15) * 8;
#pragma unroll 1
    for (int s = 0; s < 8; ++s) {
        int lr = s * 16 + sn;
        long n = base + lr;
        ushort8v o;
        if (n < N) {
            o = agg_node<FIRST>(n, cc, ptr, edata, comb, dis, root, bnsc, bnsh, zin, hb, fi);
            *reinterpret_cast<ushort8v*>(hb + n * HID + cc) = o;
        } else {
            ushort8v z8 = {0, 0, 0, 0, 0, 0, 0, 0};
            o = z8;
        }
        *reinterpret_cast<ushort8v*>(&hs[lr][cc]) = o;
    }
    __syncthreads();

    // ---- Phase B: z = hs @ Wb^T + bias ----
    int wave = tid >> 6;
    int lane = tid & 63;
    int l15 = lane & 15;
    int q = lane >> 4;
    int rowl0 = wave * 32;

    short8 a[2][4];
#pragma unroll
    for (int mt = 0; mt < 2; ++mt) {
        int rl = rowl0 + mt * 16 + l15;
#pragma unroll
        for (int kb = 0; kb < 4; ++kb)
            a[mt][kb] = *reinterpret_cast<const short8*>(&hs[rl][q * 8 + kb * 32]);
    }

    floatx4 acc[2][8];
#pragma unroll
    for (int mt = 0; mt < 2; ++mt)
#pragma unroll
        for (int nt = 0; nt < 8; ++nt) {
            floatx4 zz = {0.f, 0.f, 0.f, 0.f};
            acc[mt][nt] = zz;
        }

#pragma unroll
    for (int nt = 0; nt < 8; ++nt) {
        const unsigned short* bp = Wb + (nt * 16 + l15) * HID + q * 8;
#pragma unroll
        for (int kb = 0; kb < 4; ++kb) {
            short8 b = *reinterpret_cast<const short8*>(bp + kb * 32);
            acc[0][nt] = __builtin_amdgcn_mfma_f32_16x16x32_bf16(a[0][kb], b, acc[0][nt], 0, 0, 0);
            acc[1][nt] = __builtin_amdgcn_mfma_f32_16x16x32_bf16(a[1][kb], b, acc[1][nt], 0, 0, 0);
        }
    }

    float bi[8];
#pragma unroll
    for (int nt = 0; nt < 8; ++nt) bi[nt] = bias[nt * 16 + l15];

    __syncthreads();                          // all A-reads done before C overwrite
#pragma unroll
    for (int mt = 0; mt < 2; ++mt)
#pragma unroll
        for (int r = 0; r < 4; ++r) {
            int lr = rowl0 + mt * 16 + q * 4 + r;
#pragma unroll
            for (int nt = 0; nt < 8; ++nt)
                hs[lr][l15 + 16 * nt] = f2bf(acc[mt][nt][r] + bi[nt]);
        }
    __syncthreads();

    int tr = tid >> 4;
    int tc = (tid & 15) * 8;
#pragma unroll
    for (int i = 0; i < 8; ++i) {
        int row = i * 16 + tr;
        long gr = base + row;
        if (gr < N) {
            ushort8v v = *reinterpret_cast<const ushort8v*>(&hs[row][tc]);
            *reinterpret_cast<ushort8v*>(zout + gr * HID + tc) = v;
        }
    }
}

// ---------------- z = h @ W^T + b  (standalone; initial iteration) -----------
__global__ __launch_bounds__(256) void gemm_kernel(
    const unsigned short* __restrict__ hb, const unsigned short* __restrict__ Wb,
    const float* __restrict__ bias, unsigned short* __restrict__ zb, int N)
{
    __shared__ unsigned short st[128][132];
    int wave = threadIdx.x >> 6;
    int lane = threadIdx.x & 63;
    int l15 = lane & 15;
    int q = lane >> 4;
    long row0 = (long)blockIdx.x * 128 + wave * 32;

    short8 a[2][4];
#pragma unroll
    for (int mt = 0; mt < 2; ++mt) {
        long rl = row0 + mt * 16 + l15;
        if (rl > (long)N - 1) rl = (long)N - 1;
        const unsigned short* ap = hb + rl * HID + q * 8;
#pragma unroll
        for (int kb = 0; kb < 4; ++kb)
            a[mt][kb] = *reinterpret_cast<const short8*>(ap + kb * 32);
    }

    floatx4 acc[2][8];
#pragma unroll
    for (int mt = 0; mt < 2; ++mt)
#pragma unroll
        for (int nt = 0; nt < 8; ++nt) {
            floatx4 zz = {0.f, 0.f, 0.f, 0.f};
            acc[mt][nt] = zz;
        }

#pragma unroll
    for (int nt = 0; nt < 8; ++nt) {
        const unsigned short* bp = Wb + (nt * 16 + l15) * HID + q * 8;
#pragma unroll
        for (int kb = 0; kb < 4; ++kb) {
            short8 b = *reinterpret_cast<const short8*>(bp + kb * 32);
            acc[0][nt] = __builtin_amdgcn_mfma_f32_16x16x32_bf16(a[0][kb], b, acc[0][nt], 0, 0, 0);
            acc[1][nt] = __builtin_amdgcn_mfma_f32_16x16x32_bf16(a[1][kb], b, acc[1][nt], 0, 0, 0);
        }
    }

    float bi[8];
#pragma unroll
    for (int nt = 0; nt < 8; ++nt) bi[nt] = bias[nt * 16 + l15];

#pragma unroll
    for (int mt = 0; mt < 2; ++mt)
#pragma unroll
        for (int r = 0; r < 4; ++r) {
            int lr = wave * 32 + mt * 16 + q * 4 + r;
#pragma unroll
            for (int nt = 0; nt < 8; ++nt)
                st[lr][l15 + 16 * nt] = f2bf(acc[mt][nt][r] + bi[nt]);
        }
    __syncthreads();

    int tr = threadIdx.x >> 4;
    int tc = (threadIdx.x & 15) * 8;
#pragma unroll
    for (int i = 0; i < 8; ++i) {
        int row = i * 16 + tr;
        long gr = (long)blockIdx.x * 128 + row;
        if (gr < N) {
            ushort8v v = *reinterpret_cast<const ushort8v*>(&st[row][tc]);
            *reinterpret_cast<ushort8v*>(zb + gr * HID + tc) = v;
        }
    }
}

// ---------------- final linear via MFMA ----------------
__global__ __launch_bounds__(256) void linmm_kernel(
    const unsigned short* __restrict__ pb, const unsigned short* __restrict__ Wb,
    const float* __restrict__ bias, float* __restrict__ out, int G)
{
    int wave = threadIdx.x >> 6;
    int lane = threadIdx.x & 63;
    int l15 = lane & 15;
    int q = lane >> 4;
    long row0 = (long)blockIdx.x * 128 + wave * 32;

    short8 a[2][4];
#pragma unroll
    for (int mt = 0; mt < 2; ++mt) {
        long rl = row0 + mt * 16 + l15;
        if (rl > (long)G - 1) rl = (long)G - 1;
        const unsigned short* ap = pb + rl * HID + q * 8;
#pragma unroll
        for (int kb = 0; kb < 4; ++kb)
            a[mt][kb] = *reinterpret_cast<const short8*>(ap + kb * 32);
    }

    floatx4 acc[2][8];
#pragma unroll
    for (int mt = 0; mt < 2; ++mt)
#pragma unroll
        for (int nt = 0; nt < 8; ++nt) {
            floatx4 zz = {0.f, 0.f, 0.f, 0.f};
            acc[mt][nt] = zz;
        }

#pragma unroll
    for (int nt = 0; nt < 8; ++nt) {
        const unsigned short* bp = Wb + (nt * 16 + l15) * HID + q * 8;
#pragma unroll
        for (int kb = 0; kb < 4; ++kb) {
            short8 b = *reinterpret_cast<const short8*>(bp + kb * 32);
            acc[0][nt] = __builtin_amdgcn_mfma_f32_16x16x32_bf16(a[0][kb], b, acc[0][nt], 0, 0, 0);
            acc[1][nt] = __builtin_amdgcn_mfma_f32_16x16x32_bf16(a[1][kb], b, acc[1][nt], 0, 0, 0);
        }
    }

    float bi[8];
#pragma unroll
    for (int nt = 0; nt < 8; ++nt) bi[nt] = bias[nt * 16 + l15];

#pragma unroll
    for (int mt = 0; mt < 2; ++mt)
#pragma unroll
        for (int r = 0; r < 4; ++r) {
            long rr = row0 + mt * 16 + q * 4 + r;
            if (rr < G) {
                float* op = out + rr * HID + l15;
#pragma unroll
                for (int nt = 0; nt < 8; ++nt)
                    op[nt * 16] = acc[mt][nt][r] + bi[nt];
            }
        }
}

// ---------------- mean-pool per graph -> bf16 pooled[G][128] ----------------
__global__ __launch_bounds__(256) void pool_kernel(
    const unsigned short* __restrict__ hb, const int* __restrict__ gptr,
    unsigned short* __restrict__ pb, int G)
{
    int g = blockIdx.x;
    if (g >= G) return;
    int tid = threadIdx.x;
    int sub = tid >> 5;
    int c = (tid & 31) * 4;
    int lo = gptr[g], hi = gptr[g + 1];
    floatx4 s = {0.f, 0.f, 0.f, 0.f};
    for (int n = lo + sub; n < hi; n += 8) {
        ushort4v hv = *reinterpret_cast<const ushort4v*>(hb + (long)n * HID + c);
#pragma unroll
        for (int j = 0; j < 4; ++j) s[j] += bf2f(hv[j]);
    }
    __shared__ float ps[8][HID];
    *reinterpret_cast<floatx4*>(&ps[sub][c]) = s;
    __syncthreads();
    if (tid < HID) {
        float sum = 0.f;
#pragma unroll
        for (int k = 0; k < 8; ++k) sum += ps[k][tid];
        float cnt = (hi > lo) ? (float)(hi - lo) : 1.f;
        pb[(long)g * HID + tid] = f2bf(sum / cnt);
    }
}

extern "C" void kernel_launch(void* const* d_in, const int* in_sizes, int n_in,
                              void* d_out, int out_size, void* d_ws, size_t ws_size,
                              hipStream_t stream)
{
    const int* x          = (const int*)d_in[0];
    const int* ei         = (const int*)d_in[1];
    const int* attr       = (const int*)d_in[2];
    const int* batch      = (const int*)d_in[3];
    const float* atom_emb = (const float*)d_in[4];
    const float* bond_emb = (const float*)d_in[5];
    const float* conv_W   = (const float*)d_in[6];
    const float* conv_b   = (const float*)d_in[7];
    const float* root     = (const float*)d_in[8];
    const float* gamma    = (const float*)d_in[9];
    const float* beta     = (const float*)d_in[10];
    const float* mean     = (const float*)d_in[11];
    const float* var      = (const float*)d_in[12];
    const float* lin_W    = (const float*)d_in[13];
    const float* lin_b    = (const float*)d_in[14];
    float* out = (float*)d_out;

    const int N = in_sizes[0] / 9;
    const int E = in_sizes[1] / 2;
    const int G = out_size / HID;
    const int B = (N + 255) / 256;

    auto al = [](size_t b) { return (b + 255) & ~(size_t)255; };
    const size_t baseNeed =
        al((size_t)N * HID * 2) +         // hb
        al((size_t)N * HID * 2) +         // zbA
        al((size_t)(N + 1) * 4) +         // ptr
        al((size_t)E * 8) +               // edata (int2)
        al((size_t)N * 4) +               // indeg (= cursor, in-place)
        al((size_t)2048 * 4) * 2 +        // partial + offs
        al((size_t)(G + 1) * 4) +         // gptr
        al((size_t)(G + 128) * HID * 2) + // pooled bf16 (dis aliases here; +tail pad)
        al((size_t)60 * HID * 4) +        // comb
        al((size_t)HID * 4) * 2 +         // bnsc + bnsh
        al((size_t)HID * HID * 2) * 2;    // Wb + linWb
    const size_t fusedNeed = baseNeed + al((size_t)N * HID * 2);  // + zbB

    if (ws_size < baseNeed || B > 2048) {
        float v = (B > 2048) ? 3000.f : (1000.f + (float)(ws_size >> 20));
        long n = (long)out_size;
        diag_kernel<<<(int)((n + 255) / 256), 256, 0, stream>>>(out, n, v);
        return;
    }
    const bool FUSED = (ws_size >= fusedNeed);

    char* wsp = (char*)d_ws;
    size_t used = 0;
    auto alloc = [&](size_t bytes) { char* p = wsp + used; used += al(bytes); return p; };
    unsigned short* hb  = (unsigned short*)alloc((size_t)N * HID * 2);
    unsigned short* zbA = (unsigned short*)alloc((size_t)N * HID * 2);
    int* ptr      = (int*)alloc((size_t)(N + 1) * 4);
    int2* edata   = (int2*)alloc((size_t)E * 8);
    int* indeg    = (int*)alloc((size_t)N * 4);
    int* cursor   = indeg;                    // in-place (scan2 is element-wise safe)
    int* partial  = (int*)alloc((size_t)2048 * 4);
    int* offs     = (int*)alloc((size_t)2048 * 4);
    int* gptr     = (int*)alloc((size_t)(G + 1) * 4);
    unsigned short* pb = (unsigned short*)alloc((size_t)(G + 128) * HID * 2);
    float* dis    = (float*)pb;               // alias: dis dead before pool writes pb
    float* comb   = (float*)alloc((size_t)60 * HID * 4);
    float* bnsc   = (float*)alloc((size_t)HID * 4);
    float* bnsh   = (float*)alloc((size_t)HID * 4);
    unsigned short* Wb    = (unsigned short*)alloc((size_t)HID * HID * 2);
    unsigned short* linWb = (unsigned short*)alloc((size_t)HID * HID * 2);
    unsigned short* zbB = FUSED ? (unsigned short*)alloc((size_t)N * HID * 2) : nullptr;

    // ---- prologue ----
    fillrd_kernel<<<B, 256, 0, stream>>>(dis, indeg, N);
    cvtW_kernel<<<(HID * HID + 255) / 256, 256, 0, stream>>>(conv_W, Wb);
    cvtW_kernel<<<(HID * HID + 255) / 256, 256, 0, stream>>>(lin_W, linWb);
    combemb_kernel<<<61, 128, 0, stream>>>(bond_emb, comb, gamma, beta, mean, var, bnsc, bnsh);
    encode_kernel<<<(N + 7) / 8, 256, 0, stream>>>(x, atom_emb, hb, N);
    hist_kernel<<<1024, 256, 0, stream>>>(ei, dis, indeg, E);
    fdeg_kernel<<<B, 256, 0, stream>>>(dis, N);
    bsum_kernel<<<B, 256, 0, stream>>>(indeg, partial, N);
    scan1_kernel<<<1, 256, 0, stream>>>(partial, offs, ptr, B, N);
    scan2_kernel<<<B, 256, 0, stream>>>(indeg, offs, ptr, cursor, N);
    fillcsr_kernel<<<1024, 256, 0, stream>>>(ei, attr, dis, cursor, edata, E);
    gptr_kernel<<<B, 256, 0, stream>>>(batch, gptr, N, G);

    // ---- loop (i=1 is identity, skipped; fis = {0,2,3,4}) ----
    const int gemm_blocks = (N + 127) / 128;
    const int agg_blocks  = (N + 15) / 16;
    gemm_kernel<<<gemm_blocks, 256, 0, stream>>>(hb, Wb, conv_b, zbA, N);
    if (FUSED) {
        aggemm_kernel<true ><<<gemm_blocks, 256, 0, stream>>>(ptr, edata, comb, dis, root,
                bnsc, bnsh, zbA, hb, Wb, conv_b, zbB, 0.f, N);
        aggemm_kernel<false><<<gemm_blocks, 256, 0, stream>>>(ptr, edata, comb, dis, root,
                bnsc, bnsh, zbB, hb, Wb, conv_b, zbA, 2.f, N);
        aggemm_kernel<false><<<gemm_blocks, 256, 0, stream>>>(ptr, edata, comb, dis, root,
                bnsc, bnsh, zbA, hb, Wb, conv_b, zbB, 3.f, N);
        agg_kernel<false><<<agg_blocks, 256, 0, stream>>>(ptr, edata, comb, dis, root,
                bnsc, bnsh, zbB, hb, 4.f, N);
    } else {
        const float fis[4] = {0.f, 2.f, 3.f, 4.f};
        for (int t = 0; t < 4; ++t) {
            if (t > 0)
                gemm_kernel<<<gemm_blocks, 256, 0, stream>>>(hb, Wb, conv_b, zbA, N);
            if (t == 0)
                agg_kernel<true ><<<agg_blocks, 256, 0, stream>>>(ptr, edata, comb, dis, root,
                        bnsc, bnsh, zbA, hb, fis[t], N);
            else
                agg_kernel<false><<<agg_blocks, 256, 0, stream>>>(ptr, edata, comb, dis, root,
                        bnsc, bnsh, zbA, hb, fis[t], N);
        }
    }

    // ---- mean-pool (bf16) + MFMA final linear (fp32 out) ----
    pool_kernel<<<G, 256, 0, stream>>>(hb, gptr, pb, G);
    linmm_kernel<<<(G + 127) / 128, 256, 0, stream>>>(pb, linWb, lin_b, out, G);
}

// Round 12
// 726.718 us; speedup vs baseline: 1.1810x; 1.1279x over previous
//
#include <hip/hip_runtime.h>

#define HID 128

typedef __attribute__((ext_vector_type(8))) short short8;
typedef __attribute__((ext_vector_type(8))) unsigned short ushort8v;
typedef __attribute__((ext_vector_type(4))) float floatx4;
typedef __attribute__((ext_vector_type(4))) unsigned short ushort4v;

__device__ __forceinline__ unsigned short f2bf(float f) {
    unsigned u = __builtin_bit_cast(unsigned, f);
    u += 0x7FFF + ((u >> 16) & 1);           // RNE
    return (unsigned short)(u >> 16);
}
__device__ __forceinline__ float bf2f(unsigned short s) {
    unsigned u = ((unsigned)s) << 16;
    return __builtin_bit_cast(float, u);
}

// ---------------- merged fill: dis (deg accumulator) + indeg ----------------
__global__ void fillrd_kernel(float* __restrict__ dis, int* __restrict__ indeg, int N)
{
    int i = blockIdx.x * 256 + threadIdx.x;
    if (i < N) { dis[i] = 0.f; indeg[i] = 0; }
}

// ---------------- diagnostic ----------------
__global__ void diag_kernel(float* __restrict__ out, long n, float val)
{
    long i = (long)blockIdx.x * blockDim.x + threadIdx.x;
    if (i < n) out[i] = val;
}

// ---------------- merged tables: convW->bf16, linW->bf16, comb, BN fold ------
// blocks 0..63: conv_W cvt | 64..127: lin_W cvt | 128..157: comb (2 rows/blk) | 158: BN
__global__ __launch_bounds__(256) void tables_kernel(
    const float* __restrict__ conv_W, unsigned short* __restrict__ Wb,
    const float* __restrict__ lin_W, unsigned short* __restrict__ linWb,
    const float* __restrict__ bond_emb, float* __restrict__ comb,
    const float* __restrict__ gamma, const float* __restrict__ beta,
    const float* __restrict__ mean, const float* __restrict__ var,
    float* __restrict__ bnsc, float* __restrict__ bnsh)
{
    int blk = blockIdx.x;
    int tid = threadIdx.x;
    if (blk < 64) {
        int i = blk * 256 + tid;
        Wb[i] = f2bf(conv_W[i]);
    } else if (blk < 128) {
        int i = (blk - 64) * 256 + tid;
        linWb[i] = f2bf(lin_W[i]);
    } else if (blk < 158) {
        int i = (blk - 128) * 2 + (tid >> 7);     // combo row
        int c = tid & 127;
        int a0 = i / 12, a1 = (i % 12) / 2, a2 = i % 2;
        comb[i * HID + c] = bond_emb[a0 * HID + c] + bond_emb[(5 + a1) * HID + c]
                          + bond_emb[(11 + a2) * HID + c];
    } else if (tid < HID) {
        float sc = gamma[tid] * rsqrtf(var[tid] + 1e-5f);
        bnsc[tid] = sc;
        bnsh[tid] = beta[tid] - mean[tid] * sc;
    }
}

// ---------------- merged: out-degree (row, into dis) + in-degree (col) -------
__global__ void hist_kernel(const int* __restrict__ ei, float* __restrict__ dis,
                            int* __restrict__ indeg, int E)
{
    for (int e = blockIdx.x * blockDim.x + threadIdx.x; e < E; e += gridDim.x * blockDim.x) {
        atomicAdd(&dis[ei[e]], 1.f);
        atomicAdd(&indeg[ei[E + e]], 1);
    }
}

// dis (=outdeg count) -> deg^-0.5 in place. agg recovers 1/deg as dis^2.
__global__ void fdeg_kernel(float* __restrict__ dis, int N)
{
    int n = blockIdx.x * blockDim.x + threadIdx.x;
    if (n < N) dis[n] = rsqrtf(dis[n] + 1.f);
}

// ---------------- CSR scan chain ----------------
__global__ __launch_bounds__(256) void bsum_kernel(
    const int* __restrict__ indeg, int* __restrict__ partial, int N)
{
    __shared__ int s[256];
    int i = blockIdx.x * 256 + threadIdx.x;
    s[threadIdx.x] = (i < N) ? indeg[i] : 0;
    __syncthreads();
    for (int d = 128; d > 0; d >>= 1) {
        if (threadIdx.x < d) s[threadIdx.x] += s[threadIdx.x + d];
        __syncthreads();
    }
    if (threadIdx.x == 0) partial[blockIdx.x] = s[0];
}

__global__ __launch_bounds__(256) void scan1_kernel(
    const int* __restrict__ partial, int* __restrict__ offs,
    int* __restrict__ ptr, int B, int N)
{
    __shared__ int s[256];
    __shared__ int carry_s;
    int tid = threadIdx.x;
    if (tid == 0) carry_s = 0;
    __syncthreads();
    for (int base = 0; base < B; base += 256) {
        int i = base + tid;
        int v = (i < B) ? partial[i] : 0;
        s[tid] = v;
        __syncthreads();
        for (int d = 1; d < 256; d <<= 1) {
            int t = (tid >= d) ? s[tid - d] : 0;
            __syncthreads();
            s[tid] += t;
            __syncthreads();
        }
        int carry = carry_s;
        if (i < B) offs[i] = carry + s[tid] - v;
        __syncthreads();
        if (tid == 0) carry_s = carry + s[255];
        __syncthreads();
    }
    if (tid == 0) ptr[N] = carry_s;
}

// in-place safe: cursor may alias indeg (read-before-write per element)
__global__ __launch_bounds__(256) void scan2_kernel(
    const int* __restrict__ indeg, const int* __restrict__ offs,
    int* __restrict__ ptr, int* __restrict__ cursor, int N)
{
    __shared__ int s[256];
    int tid = threadIdx.x;
    int i = blockIdx.x * 256 + tid;
    int v = (i < N) ? indeg[i] : 0;
    s[tid] = v;
    __syncthreads();
    for (int d = 1; d < 256; d <<= 1) {
        int t = (tid >= d) ? s[tid - d] : 0;
        __syncthreads();
        s[tid] += t;
        __syncthreads();
    }
    if (i < N) {
        int ex = offs[blockIdx.x] + s[tid] - v;
        ptr[i] = ex;
        cursor[i] = ex;
    }
}

// ---------------- CSR fill: packed edge record {row, ci|bf16(norm)<<16} -------
__global__ void fillcsr_kernel(const int* __restrict__ ei, const int* __restrict__ attr,
                               const float* __restrict__ dis, int* __restrict__ cursor,
                               int2* __restrict__ edata, int E)
{
    for (int e = blockIdx.x * blockDim.x + threadIdx.x; e < E; e += gridDim.x * blockDim.x) {
        int r   = ei[e];
        int col = ei[E + e];
        int pos = atomicAdd(&cursor[col], 1);
        int ci  = attr[e * 3] * 12 + attr[e * 3 + 1] * 2 + attr[e * 3 + 2];
        float nrm = dis[r] * dis[col];
        int2 ed;
        ed.x = r;
        ed.y = ci | ((int)f2bf(nrm) << 16);
        edata[pos] = ed;
    }
}

// ---------------- graph boundaries ----------------
__global__ void gptr_kernel(const int* __restrict__ batch, int* __restrict__ gptr,
                            int N, int G)
{
    int n = blockIdx.x * blockDim.x + threadIdx.x;
    if (n >= N) return;
    int b = batch[n];
    int bp = (n == 0) ? -1 : batch[n - 1];
    for (int g = bp + 1; g <= b; ++g) gptr[g] = n;
    if (n == N - 1)
        for (int g = b + 1; g <= G; ++g) gptr[g] = N;
}

// ---------------- shared agg body: one node, 8 cols (16 lanes/node) ----------
template<bool FIRST>
__device__ __forceinline__ ushort8v agg_node(
    long n, int c, const int* __restrict__ ptr, const int2* __restrict__ edata,
    const float* __restrict__ comb, const float* __restrict__ dis,
    const float* __restrict__ root, const float* __restrict__ bnsc,
    const float* __restrict__ bnsh, const unsigned short* __restrict__ zb,
    const unsigned short* __restrict__ hb, float fi)
{
    ushort8v zv = *reinterpret_cast<const ushort8v*>(zb + n * HID + c);
    ushort8v hv;
    if constexpr (!FIRST) hv = *reinterpret_cast<const ushort8v*>(hb + n * HID + c);  // hoisted
    float di = dis[n];
    float rd = di * di;                       // 1/deg
    float acc[8];
#pragma unroll
    for (int j = 0; j < 8; ++j) acc[j] = fmaxf(bf2f(zv[j]) + root[c + j], 0.f) * rd;

    int jb = ptr[n], je = ptr[n + 1];
    int j2 = jb;
    for (; j2 + 1 < je; j2 += 2) {            // paired: 2 gathers in flight
        int2 e0 = edata[j2];
        int2 e1 = edata[j2 + 1];
        ushort8v z0 = *reinterpret_cast<const ushort8v*>(zb + (long)e0.x * HID + c);
        ushort8v z1 = *reinterpret_cast<const ushort8v*>(zb + (long)e1.x * HID + c);
        const float* c0 = comb + (e0.y & 0xFF) * HID + c;
        const float* c1 = comb + (e1.y & 0xFF) * HID + c;
        float n0 = bf2f((unsigned short)(((unsigned)e0.y) >> 16));
        float n1 = bf2f((unsigned short)(((unsigned)e1.y) >> 16));
#pragma unroll
        for (int j = 0; j < 8; ++j) {
            acc[j] += fmaxf(bf2f(z0[j]) + c0[j], 0.f) * n0;
            acc[j] += fmaxf(bf2f(z1[j]) + c1[j], 0.f) * n1;
        }
    }
    if (j2 < je) {
        int2 e0 = edata[j2];
        ushort8v z0 = *reinterpret_cast<const ushort8v*>(zb + (long)e0.x * HID + c);
        const float* c0 = comb + (e0.y & 0xFF) * HID + c;
        float n0 = bf2f((unsigned short)(((unsigned)e0.y) >> 16));
#pragma unroll
        for (int j = 0; j < 8; ++j) acc[j] += fmaxf(bf2f(z0[j]) + c0[j], 0.f) * n0;
    }

    ushort8v o;
#pragma unroll
    for (int j = 0; j < 8; ++j) {
        float t = fmaxf(acc[j], 0.f) * bnsc[c + j] + bnsh[c + j];
        float h;
        if constexpr (FIRST) h = t;
        else h = fi * bf2f(hv[j]) + (1.f - fi) * t;
        o[j] = f2bf(h);
    }
    return o;
}

// ---------------- standalone agg (high-occupancy; the latency-bound loop) ----
template<bool FIRST>
__global__ __launch_bounds__(256) void agg_kernel(
    const int* __restrict__ ptr, const int2* __restrict__ edata,
    const float* __restrict__ comb, const float* __restrict__ dis,
    const float* __restrict__ root, const float* __restrict__ bnsc,
    const float* __restrict__ bnsh, const unsigned short* __restrict__ zb,
    unsigned short* __restrict__ hb, float fi, int N)
{
    long n = (long)blockIdx.x * 16 + (threadIdx.x >> 4);
    if (n >= N) return;
    int c = (threadIdx.x & 15) * 8;
    ushort8v o = agg_node<FIRST>(n, c, ptr, edata, comb, dis, root, bnsc, bnsh, zb, hb, fi);
    *reinterpret_cast<ushort8v*>(hb + n * HID + c) = o;
}

// ---------------- fused encode + gemm#1: h0 (LDS only) -> z = h0 W^T + b -----
// h0 is consumed ONLY by gemm#1 (agg-FIRST ignores old h) -> never hits global.
__global__ __launch_bounds__(256) void egemm_kernel(
    const int* __restrict__ x, const float* __restrict__ atom_emb,
    const unsigned short* __restrict__ Wb, const float* __restrict__ bias,
    unsigned short* __restrict__ zb, int N)
{
    __shared__ unsigned short hs[128][132];
    int tid = threadIdx.x;
    long base = (long)blockIdx.x * 128;
    const int OFF[9] = {0, 119, 123, 135, 147, 157, 163, 169, 171};

    // phase A: embedding sums (L2-hot table, no serial chains)
    int sn = tid >> 4;
    int cc = (tid & 15) * 8;
#pragma unroll 1
    for (int s = 0; s < 8; ++s) {
        int lr = s * 16 + sn;
        long n = base + lr;
        ushort8v o;
        if (n < N) {
            float acc[8];
#pragma unroll
            for (int j = 0; j < 8; ++j) acc[j] = 0.f;
#pragma unroll
            for (int f = 0; f < 9; ++f) {
                int idx = x[n * 9 + f] + OFF[f];
                const float* ep = atom_emb + (long)idx * HID + cc;
                floatx4 v0 = *reinterpret_cast<const floatx4*>(ep);
                floatx4 v1 = *reinterpret_cast<const floatx4*>(ep + 4);
#pragma unroll
                for (int j = 0; j < 4; ++j) { acc[j] += v0[j]; acc[j + 4] += v1[j]; }
            }
#pragma unroll
            for (int j = 0; j < 8; ++j) o[j] = f2bf(acc[j]);
        } else {
            ushort8v z8 = {0, 0, 0, 0, 0, 0, 0, 0};
            o = z8;
        }
        *reinterpret_cast<ushort8v*>(&hs[lr][cc]) = o;
    }
    __syncthreads();

    // phase B: MFMA from LDS
    int wave = tid >> 6;
    int lane = tid & 63;
    int l15 = lane & 15;
    int q = lane >> 4;
    int rowl0 = wave * 32;

    short8 a[2][4];
#pragma unroll
    for (int mt = 0; mt < 2; ++mt) {
        int rl = rowl0 + mt * 16 + l15;
#pragma unroll
        for (int kb = 0; kb < 4; ++kb)
            a[mt][kb] = *reinterpret_cast<const short8*>(&hs[rl][q * 8 + kb * 32]);
    }

    floatx4 acc[2][8];
#pragma unroll
    for (int mt = 0; mt < 2; ++mt)
#pragma unroll
        for (int nt = 0; nt < 8; ++nt) {
            floatx4 zz = {0.f, 0.f, 0.f, 0.f};
            acc[mt][nt] = zz;
        }

#pragma unroll
    for (int nt = 0; nt < 8; ++nt) {
        const unsigned short* bp = Wb + (nt * 16 + l15) * HID + q * 8;
#pragma unroll
        for (int kb = 0; kb < 4; ++kb) {
            short8 b = *reinterpret_cast<const short8*>(bp + kb * 32);
            acc[0][nt] = __builtin_amdgcn_mfma_f32_16x16x32_bf16(a[0][kb], b, acc[0][nt], 0, 0, 0);
            acc[1][nt] = __builtin_amdgcn_mfma_f32_16x16x32_bf16(a[1][kb], b, acc[1][nt], 0, 0, 0);
        }
    }

    float bi[8];
#pragma unroll
    for (int nt = 0; nt < 8; ++nt) bi[nt] = bias[nt * 16 + l15];

    __syncthreads();
#pragma unroll
    for (int mt = 0; mt < 2; ++mt)
#pragma unroll
        for (int r = 0; r < 4; ++r) {
            int lr = rowl0 + mt * 16 + q * 4 + r;
#pragma unroll
            for (int nt = 0; nt < 8; ++nt)
                hs[lr][l15 + 16 * nt] = f2bf(acc[mt][nt][r] + bi[nt]);
        }
    __syncthreads();

    int tr = tid >> 4;
    int tc = (tid & 15) * 8;
#pragma unroll
    for (int i = 0; i < 8; ++i) {
        int row = i * 16 + tr;
        long gr = base + row;
        if (gr < N) {
            ushort8v v = *reinterpret_cast<const ushort8v*>(&hs[row][tc]);
            *reinterpret_cast<ushort8v*>(zb + gr * HID + tc) = v;
        }
    }
}

// ---------------- z = h @ W^T + b  (standalone) ----------------
__global__ __launch_bounds__(256) void gemm_kernel(
    const unsigned short* __restrict__ hb, const unsigned short* __restrict__ Wb,
    const float* __restrict__ bias, unsigned short* __restrict__ zb, int N)
{
    __shared__ unsigned short st[128][132];
    int wave = threadIdx.x >> 6;
    int lane = threadIdx.x & 63;
    int l15 = lane & 15;
    int q = lane >> 4;
    long row0 = (long)blockIdx.x * 128 + wave * 32;

    short8 a[2][4];
#pragma unroll
    for (int mt = 0; mt < 2; ++mt) {
        long rl = row0 + mt * 16 + l15;
        if (rl > (long)N - 1) rl = (long)N - 1;
        const unsigned short* ap = hb + rl * HID + q * 8;
#pragma unroll
        for (int kb = 0; kb < 4; ++kb)
            a[mt][kb] = *reinterpret_cast<const short8*>(ap + kb * 32);
    }

    floatx4 acc[2][8];
#pragma unroll
    for (int mt = 0; mt < 2; ++mt)
#pragma unroll
        for (int nt = 0; nt < 8; ++nt) {
            floatx4 zz = {0.f, 0.f, 0.f, 0.f};
            acc[mt][nt] = zz;
        }

#pragma unroll
    for (int nt = 0; nt < 8; ++nt) {
        const unsigned short* bp = Wb + (nt * 16 + l15) * HID + q * 8;
#pragma unroll
        for (int kb = 0; kb < 4; ++kb) {
            short8 b = *reinterpret_cast<const short8*>(bp + kb * 32);
            acc[0][nt] = __builtin_amdgcn_mfma_f32_16x16x32_bf16(a[0][kb], b, acc[0][nt], 0, 0, 0);
            acc[1][nt] = __builtin_amdgcn_mfma_f32_16x16x32_bf16(a[1][kb], b, acc[1][nt], 0, 0, 0);
        }
    }

    float bi[8];
#pragma unroll
    for (int nt = 0; nt < 8; ++nt) bi[nt] = bias[nt * 16 + l15];

#pragma unroll
    for (int mt = 0; mt < 2; ++mt)
#pragma unroll
        for (int r = 0; r < 4; ++r) {
            int lr = wave * 32 + mt * 16 + q * 4 + r;
#pragma unroll
            for (int nt = 0; nt < 8; ++nt)
                st[lr][l15 + 16 * nt] = f2bf(acc[mt][nt][r] + bi[nt]);
        }
    __syncthreads();

    int tr = threadIdx.x >> 4;
    int tc = (threadIdx.x & 15) * 8;
#pragma unroll
    for (int i = 0; i < 8; ++i) {
        int row = i * 16 + tr;
        long gr = (long)blockIdx.x * 128 + row;
        if (gr < N) {
            ushort8v v = *reinterpret_cast<const ushort8v*>(&st[row][tc]);
            *reinterpret_cast<ushort8v*>(zb + gr * HID + tc) = v;
        }
    }
}

// ---------------- final linear via MFMA ----------------
__global__ __launch_bounds__(256) void linmm_kernel(
    const unsigned short* __restrict__ pb, const unsigned short* __restrict__ Wb,
    const float* __restrict__ bias, float* __restrict__ out, int G)
{
    int wave = threadIdx.x >> 6;
    int lane = threadIdx.x & 63;
    int l15 = lane & 15;
    int q = lane >> 4;
    long row0 = (long)blockIdx.x * 128 + wave * 32;

    short8 a[2][4];
#pragma unroll
    for (int mt = 0; mt < 2; ++mt) {
        long rl = row0 + mt * 16 + l15;
        if (rl > (long)G - 1) rl = (long)G - 1;
        const unsigned short* ap = pb + rl * HID + q * 8;
#pragma unroll
        for (int kb = 0; kb < 4; ++kb)
            a[mt][kb] = *reinterpret_cast<const short8*>(ap + kb * 32);
    }

    floatx4 acc[2][8];
#pragma unroll
    for (int mt = 0; mt < 2; ++mt)
#pragma unroll
        for (int nt = 0; nt < 8; ++nt) {
            floatx4 zz = {0.f, 0.f, 0.f, 0.f};
            acc[mt][nt] = zz;
        }

#pragma unroll
    for (int nt = 0; nt < 8; ++nt) {
        const unsigned short* bp = Wb + (nt * 16 + l15) * HID + q * 8;
#pragma unroll
        for (int kb = 0; kb < 4; ++kb) {
            short8 b = *reinterpret_cast<const short8*>(bp + kb * 32);
            acc[0][nt] = __builtin_amdgcn_mfma_f32_16x16x32_bf16(a[0][kb], b, acc[0][nt], 0, 0, 0);
            acc[1][nt] = __builtin_amdgcn_mfma_f32_16x16x32_bf16(a[1][kb], b, acc[1][nt], 0, 0, 0);
        }
    }

    float bi[8];
#pragma unroll
    for (int nt = 0; nt < 8; ++nt) bi[nt] = bias[nt * 16 + l15];

#pragma unroll
    for (int mt = 0; mt < 2; ++mt)
#pragma unroll
        for (int r = 0; r < 4; ++r) {
            long rr = row0 + mt * 16 + q * 4 + r;
            if (rr < G) {
                float* op = out + rr * HID + l15;
#pragma unroll
                for (int nt = 0; nt < 8; ++nt)
                    op[nt * 16] = acc[mt][nt][r] + bi[nt];
            }
        }
}

// ---------------- mean-pool per graph -> bf16 pooled[G][128] ----------------
__global__ __launch_bounds__(256) void pool_kernel(
    const unsigned short* __restrict__ hb, const int* __restrict__ gptr,
    unsigned short* __restrict__ pb, int G)
{
    int g = blockIdx.x;
    if (g >= G) return;
    int tid = threadIdx.x;
    int sub = tid >> 5;
    int c = (tid & 31) * 4;
    int lo = gptr[g], hi = gptr[g + 1];
    floatx4 s = {0.f, 0.f, 0.f, 0.f};
    for (int n = lo + sub; n < hi; n += 8) {
        ushort4v hv = *reinterpret_cast<const ushort4v*>(hb + (long)n * HID + c);
#pragma unroll
        for (int j = 0; j < 4; ++j) s[j] += bf2f(hv[j]);
    }
    __shared__ float ps[8][HID];
    *reinterpret_cast<floatx4*>(&ps[sub][c]) = s;
    __syncthreads();
    if (tid < HID) {
        float sum = 0.f;
#pragma unroll
        for (int k = 0; k < 8; ++k) sum += ps[k][tid];
        float cnt = (hi > lo) ? (float)(hi - lo) : 1.f;
        pb[(long)g * HID + tid] = f2bf(sum / cnt);
    }
}

extern "C" void kernel_launch(void* const* d_in, const int* in_sizes, int n_in,
                              void* d_out, int out_size, void* d_ws, size_t ws_size,
                              hipStream_t stream)
{
    const int* x          = (const int*)d_in[0];
    const int* ei         = (const int*)d_in[1];
    const int* attr       = (const int*)d_in[2];
    const int* batch      = (const int*)d_in[3];
    const float* atom_emb = (const float*)d_in[4];
    const float* bond_emb = (const float*)d_in[5];
    const float* conv_W   = (const float*)d_in[6];
    const float* conv_b   = (const float*)d_in[7];
    const float* root     = (const float*)d_in[8];
    const float* gamma    = (const float*)d_in[9];
    const float* beta     = (const float*)d_in[10];
    const float* mean     = (const float*)d_in[11];
    const float* var      = (const float*)d_in[12];
    const float* lin_W    = (const float*)d_in[13];
    const float* lin_b    = (const float*)d_in[14];
    float* out = (float*)d_out;

    const int N = in_sizes[0] / 9;
    const int E = in_sizes[1] / 2;
    const int G = out_size / HID;
    const int B = (N + 255) / 256;

    auto al = [](size_t b) { return (b + 255) & ~(size_t)255; };
    const size_t need =
        al((size_t)N * HID * 2) +         // hb
        al((size_t)N * HID * 2) +         // zb
        al((size_t)(N + 1) * 4) +         // ptr
        al((size_t)E * 8) +               // edata (int2)
        al((size_t)N * 4) +               // indeg (= cursor)
        al((size_t)2048 * 4) * 2 +        // partial + offs
        al((size_t)(G + 1) * 4) +         // gptr
        al((size_t)(G + 128) * HID * 2) + // pooled bf16 (dis aliases; +tail pad)
        al((size_t)60 * HID * 4) +        // comb
        al((size_t)HID * 4) * 2 +         // bnsc + bnsh
        al((size_t)HID * HID * 2) * 2;    // Wb + linWb

    if (ws_size < need || B > 2048) {
        float v = (B > 2048) ? 3000.f : (1000.f + (float)(ws_size >> 20));
        long n = (long)out_size;
        diag_kernel<<<(int)((n + 255) / 256), 256, 0, stream>>>(out, n, v);
        return;
    }

    char* wsp = (char*)d_ws;
    size_t used = 0;
    auto alloc = [&](size_t bytes) { char* p = wsp + used; used += al(bytes); return p; };
    unsigned short* hb = (unsigned short*)alloc((size_t)N * HID * 2);
    unsigned short* zb = (unsigned short*)alloc((size_t)N * HID * 2);
    int* ptr      = (int*)alloc((size_t)(N + 1) * 4);
    int2* edata   = (int2*)alloc((size_t)E * 8);
    int* indeg    = (int*)alloc((size_t)N * 4);
    int* cursor   = indeg;                    // in-place scan (element-wise safe)
    int* partial  = (int*)alloc((size_t)2048 * 4);
    int* offs     = (int*)alloc((size_t)2048 * 4);
    int* gptr     = (int*)alloc((size_t)(G + 1) * 4);
    unsigned short* pb = (unsigned short*)alloc((size_t)(G + 128) * HID * 2);
    float* dis    = (float*)pb;               // alias: dis dead before pool writes pb
    float* comb   = (float*)alloc((size_t)60 * HID * 4);
    float* bnsc   = (float*)alloc((size_t)HID * 4);
    float* bnsh   = (float*)alloc((size_t)HID * 4);
    unsigned short* Wb    = (unsigned short*)alloc((size_t)HID * HID * 2);
    unsigned short* linWb = (unsigned short*)alloc((size_t)HID * HID * 2);

    // ---- prologue ----
    fillrd_kernel<<<B, 256, 0, stream>>>(dis, indeg, N);
    tables_kernel<<<159, 256, 0, stream>>>(conv_W, Wb, lin_W, linWb, bond_emb, comb,
                                           gamma, beta, mean, var, bnsc, bnsh);
    hist_kernel<<<1024, 256, 0, stream>>>(ei, dis, indeg, E);
    fdeg_kernel<<<B, 256, 0, stream>>>(dis, N);
    bsum_kernel<<<B, 256, 0, stream>>>(indeg, partial, N);
    scan1_kernel<<<1, 256, 0, stream>>>(partial, offs, ptr, B, N);
    scan2_kernel<<<B, 256, 0, stream>>>(indeg, offs, ptr, cursor, N);
    fillcsr_kernel<<<1024, 256, 0, stream>>>(ei, attr, dis, cursor, edata, E);
    gptr_kernel<<<B, 256, 0, stream>>>(batch, gptr, N, G);

    // ---- loop (i=1 is identity, skipped; fis = {0,2,3,4}) ----
    const int gemm_blocks = (N + 127) / 128;
    const int agg_blocks  = (N + 15) / 16;
    egemm_kernel<<<gemm_blocks, 256, 0, stream>>>(x, atom_emb, Wb, conv_b, zb, N);
    agg_kernel<true ><<<agg_blocks, 256, 0, stream>>>(ptr, edata, comb, dis, root,
            bnsc, bnsh, zb, hb, 0.f, N);
    const float fis[3] = {2.f, 3.f, 4.f};
    for (int t = 0; t < 3; ++t) {
        gemm_kernel<<<gemm_blocks, 256, 0, stream>>>(hb, Wb, conv_b, zb, N);
        agg_kernel<false><<<agg_blocks, 256, 0, stream>>>(ptr, edata, comb, dis, root,
                bnsc, bnsh, zb, hb, fis[t], N);
    }

    // ---- mean-pool (bf16) + MFMA final linear (fp32 out) ----
    pool_kernel<<<G, 256, 0, stream>>>(hb, gptr, pb, G);
    linmm_kernel<<<(G + 127) / 128, 256, 0, stream>>>(pb, linWb, lin_b, out, G);
}